// Round 2
// baseline (19180.609 us; speedup 1.0000x reference)
//
#include <hip/hip_runtime.h>

// Problem constants
constexpr int BN   = 8;            // batch
constexpr int CIN  = 16;
constexpr int COUT = 32;
constexpr int S    = 24;           // spatial edge
constexpr int P    = S * S;        // 576 pixels per plane
constexpr int SP   = 26;           // padded edge
constexpr int PPAD = SP * SP;      // 676
constexpr int NPIX = P * P;        // 331776
constexpr float EPS = 1e-5f;

// Workspace float layout:
// [0,64)        : stats (b*4+g)*2 -> {sum, sumsq}
// [64,320)      : scale[b*32+c]
// [320,576)     : shift[b*32+c]
// [1024, ...)   : inter[b][co][ha*24+wa][hb*24+wb]  (84,934,656 floats)

__global__ void zero_stats_kernel(float* __restrict__ stats) {
    stats[threadIdx.x] = 0.f;
}

// Kernel A: conv over (hb,wb) plane + bias, write inter, accumulate GN stats.
// One block per (b, ha, wa). All 16 input planes staged into padded LDS ONCE
// (single barrier), then 16 ci of pure LDS-read + FMA with no barriers.
// Wave w handles co in [8w, 8w+8) (= GN group w). Lane l: pixels p = l + 64*j.
__global__ __launch_bounds__(256, 2)
void conv2_kernel(const float* __restrict__ x, const float* __restrict__ w2,
                  const float* __restrict__ b2, float* __restrict__ inter,
                  float* __restrict__ stats)
{
    __shared__ float xs[CIN * PPAD];         // 16 padded planes, 43,264 B
    __shared__ float wl[CIN * 9 * COUT];     // [ci*9+tap][co], 18,432 B

    const int tid = threadIdx.x;
    const int bid = blockIdx.x;
    const int b   = bid / P;
    const int haw = bid - b * P;

    // conflict-free weight staging: wl[r*32+c] = w2[c*144 + r]
    // (sequential LDS writes; strided global reads are L2-resident after warmup)
    for (int i = tid; i < CIN * 9 * COUT; i += 256)
        wl[i] = w2[(i & 31) * 144 + (i >> 5)];
    // zero all padded planes (borders must be 0)
    for (int i = tid; i < CIN * PPAD; i += 256) xs[i] = 0.f;
    __syncthreads();
    // fill interiors: 16 planes x 144 float4 = 2304 vec4 loads, 9 per thread
    for (int k = tid; k < CIN * (P / 4); k += 256) {
        const int ci = k / (P / 4);
        const int i  = (k - ci * (P / 4)) * 4;       // element in plane, %4==0
        const float4 v = *(const float4*)(x + (size_t)((b * CIN + ci) * P + haw) * P + i);
        const int hb = i / 24, wb = i - hb * 24;     // wb in {0,4,...,20}
        float* d = &xs[ci * PPAD + (hb + 1) * SP + (wb + 1)];
        d[0] = v.x; d[1] = v.y; d[2] = v.z; d[3] = v.w;
    }

    const int wave = tid >> 6, lane = tid & 63;
    const int co0 = wave * 8;

    const float4 bA = *(const float4*)(b2 + co0);
    const float4 bB = *(const float4*)(b2 + co0 + 4);
    float4 accA[9], accB[9];
    int base[9];
#pragma unroll
    for (int j = 0; j < 9; ++j) {
        accA[j] = bA; accB[j] = bB;
        const int p = lane + 64 * j;
        const int hb = p / 24, wb = p - hb * 24;
        base[j] = hb * SP + wb;                      // + kh*26 + kw covers taps
    }

    __syncthreads();

    for (int ci = 0; ci < CIN; ++ci) {
        const float* plane = &xs[ci * PPAD];
        const float* wrow  = &wl[ci * 9 * 32];
#pragma unroll
        for (int tap = 0; tap < 9; ++tap) {
            const int off = (tap / 3) * SP + (tap % 3);
            const float4 wA = *(const float4*)(wrow + tap * 32 + co0);
            const float4 wB = *(const float4*)(wrow + tap * 32 + co0 + 4);
#pragma unroll
            for (int j = 0; j < 9; ++j) {
                const float v = plane[base[j] + off];
                accA[j].x = fmaf(v, wA.x, accA[j].x);
                accA[j].y = fmaf(v, wA.y, accA[j].y);
                accA[j].z = fmaf(v, wA.z, accA[j].z);
                accA[j].w = fmaf(v, wA.w, accA[j].w);
                accB[j].x = fmaf(v, wB.x, accB[j].x);
                accB[j].y = fmaf(v, wB.y, accB[j].y);
                accB[j].z = fmaf(v, wB.z, accB[j].z);
                accB[j].w = fmaf(v, wB.w, accB[j].w);
            }
        }
    }

    // write inter + per-wave GN partial stats (post-bias values)
    float s = 0.f, ss = 0.f;
    float* dst = inter + (size_t)((b * COUT + co0) * P + haw) * P;
#pragma unroll
    for (int j = 0; j < 9; ++j) {
        const int p = lane + 64 * j;
        const float4 a = accA[j], c = accB[j];
        s  += a.x + a.y + a.z + a.w + c.x + c.y + c.z + c.w;
        ss += a.x*a.x + a.y*a.y + a.z*a.z + a.w*a.w
            + c.x*c.x + c.y*c.y + c.z*c.z + c.w*c.w;
        dst[0 * NPIX + p] = a.x; dst[1 * NPIX + p] = a.y;
        dst[2 * NPIX + p] = a.z; dst[3 * NPIX + p] = a.w;
        dst[4 * NPIX + p] = c.x; dst[5 * NPIX + p] = c.y;
        dst[6 * NPIX + p] = c.z; dst[7 * NPIX + p] = c.w;
    }
#pragma unroll
    for (int off = 32; off > 0; off >>= 1) {
        s  += __shfl_down(s, off);
        ss += __shfl_down(ss, off);
    }
    if (lane == 0) {
        atomicAdd(&stats[(b * 4 + wave) * 2 + 0], s);
        atomicAdd(&stats[(b * 4 + wave) * 2 + 1], ss);
    }
}

// Kernel B: finalize GN -> per (b,c) scale/shift
__global__ void gn_finalize_kernel(const float* __restrict__ stats,
                                   const float* __restrict__ gamma,
                                   const float* __restrict__ beta,
                                   float* __restrict__ scale,
                                   float* __restrict__ shift)
{
    const int t = threadIdx.x;           // 256 = 8b * 32c
    const int b = t >> 5, c = t & 31, g = c >> 3;
    const float sum = stats[(b * 4 + g) * 2 + 0];
    const float ssq = stats[(b * 4 + g) * 2 + 1];
    const float invN = 1.f / (8.f * (float)NPIX);
    const float mean = sum * invN;
    const float var  = ssq * invN - mean * mean;
    const float rstd = rsqrtf(var + EPS);
    const float sc   = gamma[c] * rstd;
    scale[t] = sc;
    shift[t] = beta[c] - mean * sc;
}

// Kernel C: conv over (ha,wa) plane; GN+ReLU fused on load.
// One block per (b, ha, wa). No plane staging: per-(tap,j) values are per-lane
// private, and a block's per-ci working set (9 planes ~ 21 KB) is L1-resident.
// Zero barriers in the ci loop; tap validity is block-uniform (no divergence).
__global__ __launch_bounds__(256, 4)
void conv1_kernel(const float* __restrict__ inter, const float* __restrict__ w1,
                  const float* __restrict__ b1, const float* __restrict__ scale,
                  const float* __restrict__ shift, float* __restrict__ out)
{
    __shared__ float wl[COUT * 9 * COUT];    // [ci*9+tap][co], 36,864 B
    __shared__ float sls[COUT], slh[COUT];

    const int tid = threadIdx.x;
    const int bid = blockIdx.x;
    const int b   = bid / P;
    const int haw = bid - b * P;
    const int ha  = haw / 24, wa = haw - ha * 24;

    // conflict-free weight staging: wl[r*32+c] = w1[c*288 + r]
    for (int i = tid; i < COUT * 9 * COUT; i += 256)
        wl[i] = w1[(i & 31) * 288 + (i >> 5)];
    if (tid < 32) {
        sls[tid] = scale[b * 32 + tid];
        slh[tid] = shift[b * 32 + tid];
    }

    const int wave = tid >> 6, lane = tid & 63;
    const int co0 = wave * 8;

    // block-uniform tap validity and plane offsets
    bool tv[9]; int toff[9];
#pragma unroll
    for (int tap = 0; tap < 9; ++tap) {
        const int dh = tap / 3 - 1, dw = tap % 3 - 1;
        const int ha2 = ha + dh, wa2 = wa + dw;
        tv[tap]   = ((unsigned)ha2 < 24u) && ((unsigned)wa2 < 24u);
        toff[tap] = (dh * 24 + dw) * P;
    }

    const float4 bA = *(const float4*)(b1 + co0);
    const float4 bB = *(const float4*)(b1 + co0 + 4);
    float4 accA[9], accB[9];
#pragma unroll
    for (int j = 0; j < 9; ++j) { accA[j] = bA; accB[j] = bB; }

    __syncthreads();

    for (int ci = 0; ci < COUT; ++ci) {
        const float sc = sls[ci], sh = slh[ci];
        const float* pbase = inter + (size_t)((b * COUT + ci) * P + haw) * P;
        const float* wrow  = &wl[ci * 9 * 32];
#pragma unroll
        for (int tap = 0; tap < 9; ++tap) {
            const float4 wA = *(const float4*)(wrow + tap * 32 + co0);
            const float4 wB = *(const float4*)(wrow + tap * 32 + co0 + 4);
            const float* sp = pbase + toff[tap];
            const bool ok = tv[tap];
#pragma unroll
            for (int j = 0; j < 9; ++j) {
                float v = 0.f;
                if (ok) v = fmaxf(fmaf(sp[lane + 64 * j], sc, sh), 0.f);
                accA[j].x = fmaf(v, wA.x, accA[j].x);
                accA[j].y = fmaf(v, wA.y, accA[j].y);
                accA[j].z = fmaf(v, wA.z, accA[j].z);
                accA[j].w = fmaf(v, wA.w, accA[j].w);
                accB[j].x = fmaf(v, wB.x, accB[j].x);
                accB[j].y = fmaf(v, wB.y, accB[j].y);
                accB[j].z = fmaf(v, wB.z, accB[j].z);
                accB[j].w = fmaf(v, wB.w, accB[j].w);
            }
        }
    }

    float* dst = out + (size_t)((b * COUT + co0) * P + haw) * P;
#pragma unroll
    for (int j = 0; j < 9; ++j) {
        const int p = lane + 64 * j;
        dst[0 * NPIX + p] = accA[j].x; dst[1 * NPIX + p] = accA[j].y;
        dst[2 * NPIX + p] = accA[j].z; dst[3 * NPIX + p] = accA[j].w;
        dst[4 * NPIX + p] = accB[j].x; dst[5 * NPIX + p] = accB[j].y;
        dst[6 * NPIX + p] = accB[j].z; dst[7 * NPIX + p] = accB[j].w;
    }
}

extern "C" void kernel_launch(void* const* d_in, const int* in_sizes, int n_in,
                              void* d_out, int out_size, void* d_ws, size_t ws_size,
                              hipStream_t stream) {
    const float* x       = (const float*)d_in[0];
    const float* conv1_w = (const float*)d_in[1];
    const float* conv1_b = (const float*)d_in[2];
    const float* conv2_w = (const float*)d_in[3];
    const float* conv2_b = (const float*)d_in[4];
    const float* gamma   = (const float*)d_in[5];
    const float* beta    = (const float*)d_in[6];
    float* out = (float*)d_out;

    float* wsf   = (float*)d_ws;
    float* stats = wsf;            // 64 floats
    float* scale = wsf + 64;       // 256 floats
    float* shift = wsf + 320;      // 256 floats
    float* inter = wsf + 1024;     // 84,934,656 floats

    zero_stats_kernel<<<1, 64, 0, stream>>>(stats);
    conv2_kernel<<<BN * P, 256, 0, stream>>>(x, conv2_w, conv2_b, inter, stats);
    gn_finalize_kernel<<<1, 256, 0, stream>>>(stats, gamma, beta, scale, shift);
    conv1_kernel<<<BN * P, 256, 0, stream>>>(inter, conv1_w, conv1_b,
                                             scale, shift, out);
}